// Round 4
// baseline (5228.633 us; speedup 1.0000x reference)
//
#include <hip/hip_runtime.h>

#define B_ 2048
#define T_ 128
#define S_ 256
#define V_ 29

// Swizzled float4 index for enc quad (s, h4). Proven conflict-free for the
// row pattern (P1/staging); P2 uses scalar b32 reads (any permutation of a
// 64-float row across 64 lanes = 2 lanes/bank = free).
__device__ __forceinline__ int enc_idx(int s, int h4) {
    return s * 16 + ((h4 + s + (s >> 4)) & 15);
}

// ---------------------------------------------------------------------------
// Precompute (1 block, 512 threads). Decoder thread t = w*64+l owns the
// (xhalf = l&1) half of gate row g = q*64 + j, q=(l>>1)&3, j=w*8+(l>>3).
//   ws[0 .. 29*256)        geR[v][g]  = b_ih[g]+b_hh[g]+emb[v]·W_ih[g,0:32]
//   ws[29*256 .. +512*64)  wcatP[t][0:64] = xhalf? W_hh[g][0:64] : W_ih[g][32:96]
// ---------------------------------------------------------------------------
__global__ __launch_bounds__(512) void precompute_kernel(
    const float* __restrict__ emb_table, const float* __restrict__ W_ih,
    const float* __restrict__ W_hh, const float* __restrict__ b_ih,
    const float* __restrict__ b_hh, float* __restrict__ ws)
{
    const int t = threadIdx.x;
    const int w = t >> 6, l = t & 63;
    const int j = w * 8 + (l >> 3);
    const int q = (l >> 1) & 3;
    const int xhalf = l & 1;
    const int g = q * 64 + j;

    float* wcatP = ws + V_ * 256;
#pragma unroll
    for (int k = 0; k < 64; ++k)
        wcatP[t * 64 + k] = xhalf ? W_hh[g * 64 + k] : W_ih[g * 96 + 32 + k];

    if (xhalf == 0) {
        float wemb[32];
#pragma unroll
        for (int e = 0; e < 32; ++e) wemb[e] = W_ih[g * 96 + e];
        const float bb = b_ih[g] + b_hh[g];
        for (int v = 0; v < V_; ++v) {
            float acc = bb;
#pragma unroll
            for (int e = 0; e < 32; ++e) acc = fmaf(emb_table[v * 32 + e], wemb[e], acc);
            ws[v * 256 + g] = acc;
        }
    }
}

// ---------------------------------------------------------------------------
// Main decoder: 1 block = 1 batch row, 512 threads (8 waves), T=128 steps,
// 4 barriers/step. enc fp32 in LDS; per-thread state: 16 float4 gate weights
// (half-row), 2 float4 fc weights, c in a register.
// ---------------------------------------------------------------------------
__global__ __launch_bounds__(512, 4) void decoder_kernel(
    const int* __restrict__ y, const float* __restrict__ h0,
    const float* __restrict__ c0, const float* __restrict__ enc,
    const float* __restrict__ fc_W, const float* __restrict__ fc_b,
    const float* __restrict__ ws, float* __restrict__ out)
{
    __shared__ float4 encS[S_ * 16];                  // 64 KB, swizzled
    __shared__ __align__(16) float attnL[S_];         // e values, linear
    __shared__ __align__(16) float ctxv[64];          // context (atomic-accumulated)
    __shared__ __align__(16) float hbuf[2][64];       // double-buffered h
    __shared__ __align__(16) float red[8 * 32];       // logits partials
    __shared__ __align__(16) float redsum[8];
    __shared__ int yrow[T_];

    const int t = threadIdx.x;
    const int b = blockIdx.x;
    const int w = t >> 6;
    const int l = t & 63;

    // P3 mapping: 8-lane group covers the 4 gates of hidden j in lane pairs
    const int jq = w * 8 + (l >> 3);    // hidden index for gates
    const int q  = (l >> 1) & 3;        // gate block i/f/g/o
    const int xhalf = l & 1;            // 0: ctx half, 1: h half

    // P1 mapping: s = t>>1, hhalf = t&1
    const int s1 = t >> 1;
    const int hh = t & 1;

    // P5 mapping
    const int v5 = t & 31;
    const int jj = t >> 5;              // 0..15, k-chunk of 8

    // --- per-thread weight registers ---
    const float* wcatP = ws + V_ * 256;
    float4 w4[16];
#pragma unroll
    for (int k = 0; k < 16; ++k) w4[k] = ((const float4*)(wcatP + t * 64))[k];

    float4 fcw[2];
    if (v5 < V_) {
        fcw[0] = ((const float4*)(fc_W + v5 * 128 + jj * 8))[0];
        fcw[1] = ((const float4*)(fc_W + v5 * 128 + jj * 8))[1];
    } else {
        fcw[0] = make_float4(0.f, 0.f, 0.f, 0.f);
        fcw[1] = make_float4(0.f, 0.f, 0.f, 0.f);
    }
    const float fcb = (t < V_) ? fc_b[t] : 0.f;

    // --- stage enc row into LDS (swizzled), init state ---
    {
        const float4* encg = (const float4*)(enc + (size_t)b * S_ * 64);
#pragma unroll
        for (int i = 0; i < 8; ++i) {
            int f4 = i * 512 + t;
            int s = f4 >> 4, h4 = f4 & 15;
            encS[enc_idx(s, h4)] = encg[f4];
        }
    }
    if (t < 64) { hbuf[0][t] = h0[b * 64 + t]; ctxv[t] = 0.f; }
    float creg = c0[b * 64 + jq];
    if (t < T_) yrow[t] = y[b * T_ + t];
    __syncthreads();

    const float* encF = (const float*)encS;
    // P2 addressing constants: h = l, s-range [w*32, w*32+32)
    const int p2_hq = l >> 2, p2_hlow = l & 3;
    const int p2_s0 = w * 32;
    const int p2_m0 = p2_hq + p2_s0 + (p2_s0 >> 4);   // h4 + s + (s>>4), i-part added per iter

    for (int tt = 0; tt < T_; ++tt) {
        const int cur = tt & 1, nxt = cur ^ 1;
        const int yt = yrow[tt];
        const float ge = ws[yt * 256 + q * 64 + jq];  // geR, L1/L2-hot

        // ---- P1: half-score for s = t>>1 over 32 h; pair-combine; exp
        {
            float sc = 0.f;
#pragma unroll
            for (int k = 0; k < 8; ++k) {
                float4 e4 = encS[enc_idx(s1, hh * 8 + k)];
                float4 h4v = *(const float4*)&hbuf[cur][4 * (hh * 8 + k)];
                sc += e4.x * h4v.x + e4.y * h4v.y + e4.z * h4v.z + e4.w * h4v.w;
            }
            sc += __shfl_xor(sc, 1);                  // full 64-h score
            float e = __expf(fminf(sc, 60.f));
            float ssum = e;                           // counts each s twice
#pragma unroll
            for (int off = 32; off >= 1; off >>= 1) ssum += __shfl_xor(ssum, off);
            if (hh == 0) attnL[s1] = e;
            if (l == 0) redsum[w] = ssum;
        }
        __syncthreads();  // BA

        // ---- P2: context partial: h = l, 32 s; scalar conflict-free reads;
        //      LDS atomic accumulate with normalization folded in.
        {
            float4 r0 = *(const float4*)&redsum[0];
            float4 r1 = *(const float4*)&redsum[4];
            const float tot = (r0.x + r0.y + r0.z + r0.w) + (r1.x + r1.y + r1.z + r1.w);
            const float inv = 2.0f * __builtin_amdgcn_rcpf(tot);  // each e counted twice
            float part = 0.f;
#pragma unroll
            for (int jb = 0; jb < 8; ++jb) {
                float4 a4 = *(const float4*)&attnL[p2_s0 + 4 * jb];
#pragma unroll
                for (int qq = 0; qq < 4; ++qq) {
                    const int i = 4 * jb + qq;                    // compile-time
                    const int col = (p2_m0 + i + (i >> 4)) & 15;  // 1 and + base
                    const float ev = encF[(p2_s0 + i) * 64 + col * 4 + p2_hlow];
                    part = fmaf((&a4.x)[qq], ev, part);
                }
            }
            atomicAdd(&ctxv[l], part * inv);
        }
        __syncthreads();  // BB

        // ---- P3: half gate row (64 FMA) + pair combine + quad-exchange LSTM
        {
            const float* xbase = xhalf ? &hbuf[cur][0] : &ctxv[0];
            float gacc = 0.f;
#pragma unroll
            for (int k = 0; k < 16; ++k) {
                float4 x4 = *(const float4*)&xbase[4 * k];
                gacc += w4[k].x * x4.x + w4[k].y * x4.y + w4[k].z * x4.z + w4[k].w * x4.w;
            }
            gacc += __shfl_xor(gacc, 1);              // full 128-dot
            gacc += ge;
            const float v2 = __shfl_xor(gacc, 2);     // gate q^1
            const float v4 = __shfl_xor(gacc, 4);     // gate q^2
            const float v6 = __shfl_xor(v2, 4);       // gate q^3
            const bool b1 = q & 1, b2 = q & 2;
            const float gi = b2 ? (b1 ? v6 : v4) : (b1 ? v2 : gacc);
            const float gf = b2 ? (b1 ? v4 : v6) : (b1 ? gacc : v2);
            const float gg = b2 ? (b1 ? v2 : gacc) : (b1 ? v6 : v4);
            const float go = b2 ? (b1 ? gacc : v2) : (b1 ? v4 : v6);
            const float si = __builtin_amdgcn_rcpf(1.f + __expf(-gi));
            const float sf = __builtin_amdgcn_rcpf(1.f + __expf(-gf));
            const float so = __builtin_amdgcn_rcpf(1.f + __expf(-go));
            const float tg = 1.f - 2.f * __builtin_amdgcn_rcpf(__expf(2.f * gg) + 1.f);
            creg = sf * creg + si * tg;
            const float hn = so * (1.f - 2.f * __builtin_amdgcn_rcpf(__expf(2.f * creg) + 1.f));
            if ((l & 7) == 0) hbuf[nxt][jq] = hn;
        }
        __syncthreads();  // BD

        // ---- P5: logits; combined = [h_new | ctx], thread (v5, jj) does 8 k's
        {
            const float* basep = (jj < 8) ? &hbuf[nxt][8 * jj] : &ctxv[8 * jj - 64];
            float4 c0v = *(const float4*)(basep);
            float4 c1v = *(const float4*)(basep + 4);
            float acc = fcw[0].x * c0v.x + fcw[0].y * c0v.y + fcw[0].z * c0v.z + fcw[0].w * c0v.w
                      + fcw[1].x * c1v.x + fcw[1].y * c1v.y + fcw[1].z * c1v.z + fcw[1].w * c1v.w;
            acc += __shfl_xor(acc, 32);               // fold jj pairs
            if ((t & 32) == 0) red[w * 32 + v5] = acc;
        }
        __syncthreads();  // BE
        if (t < V_) {
            float r = fcb;
#pragma unroll
            for (int p = 0; p < 8; ++p) r += red[p * 32 + t];
            out[((size_t)b * T_ + tt) * V_ + t] = r;
        } else if (t >= 64 && t < 128) {
            ctxv[t - 64] = 0.f;                       // re-zero for next step
        }
        // attnL/redsum rewritten only pre-next-BA; ctxv re-accumulated post-BA. Safe.
    }
}

extern "C" void kernel_launch(void* const* d_in, const int* in_sizes, int n_in,
                              void* d_out, int out_size, void* d_ws, size_t ws_size,
                              hipStream_t stream)
{
    const int*   y    = (const int*)  d_in[0];
    const float* h0   = (const float*)d_in[1];
    const float* c0   = (const float*)d_in[2];
    const float* enc  = (const float*)d_in[3];
    const float* emb  = (const float*)d_in[4];
    const float* W_ih = (const float*)d_in[5];
    const float* W_hh = (const float*)d_in[6];
    const float* b_ih = (const float*)d_in[7];
    const float* b_hh = (const float*)d_in[8];
    const float* fc_W = (const float*)d_in[9];
    const float* fc_b = (const float*)d_in[10];
    float* ws  = (float*)d_ws;   // needs (29*256 + 512*64)*4 = 157 KB
    float* out = (float*)d_out;

    precompute_kernel<<<1, 512, 0, stream>>>(emb, W_ih, W_hh, b_ih, b_hh, ws);
    decoder_kernel<<<B_, 512, 0, stream>>>(y, h0, c0, enc, fc_W, fc_b, ws, out);
}

// Round 5
// 2457.024 us; speedup vs baseline: 2.1280x; 2.1280x over previous
//
#include <hip/hip_runtime.h>

#define B_ 2048
#define T_ 128
#define S_ 256
#define V_ 29

// Swizzled float4 index for enc quad (s, h4). Row pattern (P1/staging) measured
// conflict-free (R1/R3); P2 uses scalar b32 reads of a full 64-float row across
// 64 lanes (2 lanes/bank = free, m136).
__device__ __forceinline__ int enc_idx(int s, int h4) {
    return s * 16 + ((h4 + s + (s >> 4)) & 15);
}

// ---------------------------------------------------------------------------
// Precompute (1 block, 512 threads). Decoder thread t = w*64+l owns the
// (xhalf = l&1) half of gate row g = q*64 + j, q=(l>>1)&3, j=w*8+(l>>3).
//   ws[0 .. 29*256)        geR[v][g]  = b_ih[g]+b_hh[g]+emb[v]·W_ih[g,0:32]
//   ws[29*256 .. +512*64)  wcatP[t][0:64] = xhalf? W_hh[g][0:64] : W_ih[g][32:96]
// ---------------------------------------------------------------------------
__global__ __launch_bounds__(512) void precompute_kernel(
    const float* __restrict__ emb_table, const float* __restrict__ W_ih,
    const float* __restrict__ W_hh, const float* __restrict__ b_ih,
    const float* __restrict__ b_hh, float* __restrict__ ws)
{
    const int t = threadIdx.x;
    const int w = t >> 6, l = t & 63;
    const int j = w * 8 + (l >> 3);
    const int q = (l >> 1) & 3;
    const int xhalf = l & 1;
    const int g = q * 64 + j;

    float* wcatP = ws + V_ * 256;
#pragma unroll
    for (int k = 0; k < 64; ++k)
        wcatP[t * 64 + k] = xhalf ? W_hh[g * 64 + k] : W_ih[g * 96 + 32 + k];

    if (xhalf == 0) {
        float wemb[32];
#pragma unroll
        for (int e = 0; e < 32; ++e) wemb[e] = W_ih[g * 96 + e];
        const float bb = b_ih[g] + b_hh[g];
        for (int v = 0; v < V_; ++v) {
            float acc = bb;
#pragma unroll
            for (int e = 0; e < 32; ++e) acc = fmaf(emb_table[v * 32 + e], wemb[e], acc);
            ws[v * 256 + g] = acc;
        }
    }
}

// ---------------------------------------------------------------------------
// Main decoder: 1 block = 1 batch row, 512 threads (8 waves), T=128 steps,
// 4 barriers/step, 16 waves/CU. No LDS atomics. Sparse context pass.
// __launch_bounds__ 2nd arg is BLOCKS/CU on this toolchain (R4 evidence:
// (512,4) -> VGPR 64). (512,2) -> 128-VGPR cap -> 2 blocks/CU co-resident.
// ---------------------------------------------------------------------------
__global__ __launch_bounds__(512, 2) void decoder_kernel(
    const int* __restrict__ y, const float* __restrict__ h0,
    const float* __restrict__ c0, const float* __restrict__ enc,
    const float* __restrict__ fc_W, const float* __restrict__ fc_b,
    const float* __restrict__ ws, float* __restrict__ out)
{
    __shared__ float4 encS[S_ * 16];                  // 64 KB, swizzled
    __shared__ __align__(16) float attnL[S_];         // e values (1 KB)
    __shared__ float ctxpart[8 * 64];                 // per-wave ctx partials (2 KB)
    __shared__ __align__(16) float ctxv[64];          // combined context
    __shared__ __align__(16) float hbuf[2][64];       // double-buffered h
    __shared__ __align__(16) float red[8 * 32];       // logit partials (1 KB)
    __shared__ __align__(16) float redsum[8];
    __shared__ int yrow[T_];

    const int t = threadIdx.x;
    const int b = blockIdx.x;
    const int w = t >> 6;
    const int l = t & 63;

    // P3 mapping: 8-lane group = 4 gates x 2 halves of hidden jq
    const int jq = w * 8 + (l >> 3);
    const int q  = (l >> 1) & 3;
    const int xhalf = l & 1;
    const int gofs = q * 64 + jq;

    // P1 mapping: s = t>>1, hh = t&1 (half the h-range each)
    const int s1 = t >> 1;
    const int hh = t & 1;

    // P5 mapping
    const int v5r = t & 31;
    const int jj = t >> 5;                            // 0..15, k-chunk of 8
    const int v5 = (v5r < V_) ? v5r : 0;

    // --- per-thread weight registers (loop-invariant) ---
    const float* wcatP = ws + V_ * 256;
    float4 w4[16];
#pragma unroll
    for (int k = 0; k < 16; ++k) w4[k] = ((const float4*)(wcatP + t * 64))[k];

    float4 fcw0 = ((const float4*)(fc_W + v5 * 128 + jj * 8))[0];
    float4 fcw1 = ((const float4*)(fc_W + v5 * 128 + jj * 8))[1];
    if (v5r >= V_) { fcw0 = make_float4(0.f,0.f,0.f,0.f); fcw1 = make_float4(0.f,0.f,0.f,0.f); }
    const float fcb = (t < V_) ? fc_b[t] : 0.f;

    // --- stage enc row into LDS (swizzled, coalesced), init state ---
    {
        const float4* encg = (const float4*)(enc + (size_t)b * S_ * 64);
#pragma unroll
        for (int i = 0; i < 8; ++i) {
            int f4 = i * 512 + t;
            int s = f4 >> 4, h4 = f4 & 15;
            encS[enc_idx(s, h4)] = encg[f4];
        }
    }
    if (t < 64) hbuf[0][t] = h0[b * 64 + t];
    float creg = c0[b * 64 + jq];                     // c state in a register
    if (t < T_) yrow[t] = y[b * T_ + t];
    __syncthreads();

    const float* encF = (const float*)encS;
    // P2 constants: lane = h = l, s-chunk [w*32, w*32+32)
    const int p2hq = l >> 2, p2hlow = l & 3;
    const int p2s0 = w * 32;
    const int p2c0 = p2hq + p2s0 + (p2s0 >> 4);       // swizzle base (pre-&15)

    for (int tt = 0; tt < T_; ++tt) {
        const int cur = tt & 1, nxt = cur ^ 1;
        const int yt = yrow[tt];
        const float ge = ws[yt * 256 + gofs];         // geR, L1/L2-hot

        // ---- P1: half-score for s = t>>1 over 32 h; pair-combine; exp
        {
            float sc = 0.f;
#pragma unroll
            for (int k = 0; k < 8; ++k) {
                float4 e4 = encS[enc_idx(s1, hh * 8 + k)];
                float4 h4v = *(const float4*)&hbuf[cur][4 * (hh * 8 + k)];
                sc += e4.x * h4v.x + e4.y * h4v.y + e4.z * h4v.z + e4.w * h4v.w;
            }
            sc += __shfl_xor(sc, 1);                  // full 64-h score
            float e = __expf(fminf(sc, 60.f));
            float ssum = e;                           // counts each s twice
#pragma unroll
            for (int off = 32; off >= 1; off >>= 1) ssum += __shfl_xor(ssum, off);
            if (hh == 0) attnL[s1] = e;
            if (l == 0) redsum[w] = ssum;
        }
        __syncthreads();  // BA

        // ---- deferred logit store for step tt-1 (red written pre-BD(tt-1))
        if (tt > 0 && t < V_) {
            float r = fcb;
#pragma unroll
            for (int p = 0; p < 8; ++p) r += red[p * 32 + t];
            out[((size_t)b * T_ + (tt - 1)) * V_ + t] = r;
        }

        // ---- P2: sparse context partial. Lane = h, 32 s; skip 8-s groups with
        //      negligible attention mass (wave-uniform branch).
        {
            float4 r0 = *(const float4*)&redsum[0];
            float4 r1 = *(const float4*)&redsum[4];
            const float tot = (r0.x + r0.y + r0.z + r0.w) + (r1.x + r1.y + r1.z + r1.w);
            const float inv = 2.0f * __builtin_amdgcn_rcpf(tot); // each e counted 2x
            const float thresh = 5e-6f * tot;          // a_rel < 1e-5 -> drop
            float part = 0.f;
#pragma unroll
            for (int gch = 0; gch < 4; ++gch) {
                float4 a0 = *(const float4*)&attnL[p2s0 + gch * 8];
                float4 a1 = *(const float4*)&attnL[p2s0 + gch * 8 + 4];
                float m8 = fmaxf(fmaxf(fmaxf(a0.x, a0.y), fmaxf(a0.z, a0.w)),
                                 fmaxf(fmaxf(a1.x, a1.y), fmaxf(a1.z, a1.w)));
                if (m8 >= thresh) {
#pragma unroll
                    for (int i2 = 0; i2 < 8; ++i2) {
                        const int i = gch * 8 + i2;               // compile-time
                        const int col = (p2c0 + i + (i >> 4)) & 15;
                        const float ev = encF[(p2s0 + i) * 64 + col * 4 + p2hlow];
                        const float av = (i2 < 4) ? (&a0.x)[i2] : (&a1.x)[i2 - 4];
                        part = fmaf(av, ev, part);
                    }
                }
            }
            ctxpart[w * 64 + l] = part * inv;
        }
        __syncthreads();  // BB

        // ---- combine partials (wave 0 only)
        if (t < 64) {
            float s = 0.f;
#pragma unroll
            for (int p = 0; p < 8; ++p) s += ctxpart[p * 64 + t];
            ctxv[t] = s;
        }
        __syncthreads();  // BC

        // ---- P3: half gate row (64 FMA) + pair combine + quad-exchange LSTM
        {
            const float* xbase = xhalf ? &hbuf[cur][0] : &ctxv[0];
            float gacc = 0.f;
#pragma unroll
            for (int k = 0; k < 16; ++k) {
                float4 x4 = *(const float4*)&xbase[4 * k];
                gacc += w4[k].x * x4.x + w4[k].y * x4.y + w4[k].z * x4.z + w4[k].w * x4.w;
            }
            gacc += __shfl_xor(gacc, 1);              // full 128-dot
            gacc += ge;
            const float v2 = __shfl_xor(gacc, 2);     // gate q^1
            const float v4 = __shfl_xor(gacc, 4);     // gate q^2
            const float v6 = __shfl_xor(v2, 4);       // gate q^3
            const bool b1 = q & 1, b2 = q & 2;
            const float gi = b2 ? (b1 ? v6 : v4) : (b1 ? v2 : gacc);
            const float gf = b2 ? (b1 ? v4 : v6) : (b1 ? gacc : v2);
            const float gg = b2 ? (b1 ? v2 : gacc) : (b1 ? v6 : v4);
            const float go = b2 ? (b1 ? gacc : v2) : (b1 ? v4 : v6);
            const float si = __builtin_amdgcn_rcpf(1.f + __expf(-gi));
            const float sf = __builtin_amdgcn_rcpf(1.f + __expf(-gf));
            const float so = __builtin_amdgcn_rcpf(1.f + __expf(-go));
            const float tg = 1.f - 2.f * __builtin_amdgcn_rcpf(__expf(2.f * gg) + 1.f);
            creg = sf * creg + si * tg;
            const float hn = so * (1.f - 2.f * __builtin_amdgcn_rcpf(__expf(2.f * creg) + 1.f));
            if ((l & 7) == 0) hbuf[nxt][jq] = hn;
        }
        __syncthreads();  // BD

        // ---- P5: logit partials; combined = [h_new | ctx], (v5,jj) does 8 k's
        {
            const float* basep = (jj < 8) ? &hbuf[nxt][8 * jj] : &ctxv[8 * jj - 64];
            float4 c0v = *(const float4*)(basep);
            float4 c1v = *(const float4*)(basep + 4);
            float acc = fcw0.x * c0v.x + fcw0.y * c0v.y + fcw0.z * c0v.z + fcw0.w * c0v.w
                      + fcw1.x * c1v.x + fcw1.y * c1v.y + fcw1.z * c1v.z + fcw1.w * c1v.w;
            acc += __shfl_xor(acc, 32);               // fold jj pairs
            if ((t & 32) == 0) red[w * 32 + v5r] = acc;
        }
        // no barrier: red read next iter after BA; attnL/redsum rewritten in
        // P1(t+1) whose readers all finished pre-BB(t); ctxv read by P5 here,
        // next write is combine(t+1) post-BB(t+1). Safe.
    }

    // final step's logits
    __syncthreads();
    if (t < V_) {
        float r = fcb;
#pragma unroll
        for (int p = 0; p < 8; ++p) r += red[p * 32 + t];
        out[((size_t)b * T_ + (T_ - 1)) * V_ + t] = r;
    }
}

extern "C" void kernel_launch(void* const* d_in, const int* in_sizes, int n_in,
                              void* d_out, int out_size, void* d_ws, size_t ws_size,
                              hipStream_t stream)
{
    const int*   y    = (const int*)  d_in[0];
    const float* h0   = (const float*)d_in[1];
    const float* c0   = (const float*)d_in[2];
    const float* enc  = (const float*)d_in[3];
    const float* emb  = (const float*)d_in[4];
    const float* W_ih = (const float*)d_in[5];
    const float* W_hh = (const float*)d_in[6];
    const float* b_ih = (const float*)d_in[7];
    const float* b_hh = (const float*)d_in[8];
    const float* fc_W = (const float*)d_in[9];
    const float* fc_b = (const float*)d_in[10];
    float* ws  = (float*)d_ws;   // needs (29*256 + 512*64)*4 = 157 KB
    float* out = (float*)d_out;

    precompute_kernel<<<1, 512, 0, stream>>>(emb, W_ih, W_hh, b_ih, b_hh, ws);
    decoder_kernel<<<B_, 512, 0, stream>>>(y, h0, c0, enc, fc_W, fc_b, ws, out);
}